// Round 6
// baseline (3266.224 us; speedup 1.0000x reference)
//
#include <hip/hip_runtime.h>
#include <hip/hip_bf16.h>
#include <cstddef>

#define H    50
#define G4   200   // 4*H
#define TT   1024
#define BB   512
#define BLK  448   // 7 waves: tids 0..399 = (row p=tid>>1, half hf=tid&1); 400..447 spare

__device__ __forceinline__ float sigm(float x)  { return 1.0f / (1.0f + __expf(-x)); }
__device__ __forceinline__ float tanhf_(float x){ return 1.0f - 2.0f / (__expf(2.0f * x) + 1.0f); }

__device__ __forceinline__ float4 f4mul(float4 a, float4 b) {
    return make_float4(a.x * b.x, a.y * b.y, a.z * b.z, a.w * b.w);
}
__device__ __forceinline__ float4 f4fma(float4 a, float4 b, float4 c) {
    return make_float4(__fmaf_rn(a.x, b.x, c.x), __fmaf_rn(a.y, b.y, c.y),
                       __fmaf_rn(a.z, b.z, c.z), __fmaf_rn(a.w, b.w, c.w));
}

// Half-row of 26 weights as NAMED values (6 float4 + 2 scalars).
// hf=0 covers k[0..24) via f4 (s0=s1=0); hf=1 covers k[24..48) via f4 + k48,k49.
#define HDECL(P) float4 P##_q0, P##_q1, P##_q2, P##_q3, P##_q4, P##_q5; float P##_s0, P##_s1;

#define HLOAD(P, base, hfv) do { const float* _s = (base) + (hfv) * 24; \
    P##_q0 = make_float4(_s[0],  _s[1],  _s[2],  _s[3]);  \
    P##_q1 = make_float4(_s[4],  _s[5],  _s[6],  _s[7]);  \
    P##_q2 = make_float4(_s[8],  _s[9],  _s[10], _s[11]); \
    P##_q3 = make_float4(_s[12], _s[13], _s[14], _s[15]); \
    P##_q4 = make_float4(_s[16], _s[17], _s[18], _s[19]); \
    P##_q5 = make_float4(_s[20], _s[21], _s[22], _s[23]); \
    P##_s0 = (hfv) ? (base)[48] : 0.f; P##_s1 = (hfv) ? (base)[49] : 0.f; } while (0)

// vb: 16B-aligned LDS float*; reads words [hf*24 .. hf*24+24) as f4 (aligned:
// byte offset hf*96) plus words 48,49 (zero-weighted for hf=0).
#define HDOT(P, vb, hfv, accout) do { \
    const float4* _v = (const float4*)((vb) + (hfv) * 24); \
    float4 _a = f4mul(P##_q0, _v[0]); \
    float4 _b = f4mul(P##_q1, _v[1]); \
    _a = f4fma(P##_q2, _v[2], _a); _b = f4fma(P##_q3, _v[3], _b); \
    _a = f4fma(P##_q4, _v[4], _a); _b = f4fma(P##_q5, _v[5], _b); \
    float _r = (_a.x + _b.x) + (_a.y + _b.y) + ((_a.z + _b.z) + (_a.w + _b.w)); \
    _r = __fmaf_rn(P##_s0, (vb)[48], _r); \
    _r = __fmaf_rn(P##_s1, (vb)[49], _r); \
    (accout) = _r; } while (0)

// MODE 0: first layer (scalar x input, write h-seq)
// MODE 1: middle layer (vector input, write h-seq; in-place on ws is safe)
// MODE 2: last layer (vector input, no h-seq write, fused dense head)
template <int MODE>
__global__ __launch_bounds__(BLK, 3) void lstm_kernel(
    const float* __restrict__ xin,     // MODE0: x [B][T]; else h_prev [B][T][H]
    const float* __restrict__ w_ih,    // [G4][H] (MODE0: [G4][1])
    const float* __restrict__ w_hh,    // [G4][H]
    const float* __restrict__ b_ih,    // [G4]
    const float* __restrict__ b_hh,    // [G4]
    float* __restrict__ hout,          // [B][T][H]  (MODE 0,1)
    const float* __restrict__ w_dense, // [H]    (MODE 2)
    const float* __restrict__ b_dense, // [1]    (MODE 2)
    float* __restrict__ out)           // [B]    (MODE 2)
{
    const int b   = blockIdx.x;
    const int tid = threadIdx.x;
    const int wv  = tid >> 6;   // wave 0..6
    const int ln  = tid & 63;   // lane
    const int p   = tid >> 1;   // gate row (tid<400 active)
    const int hf  = tid & 1;    // k-half
    const bool rower = (tid < 2 * G4);
    const int pr  = rower ? p : (G4 - 1);   // clamp: spares compute garbage, discarded

    __shared__ __align__(16) float h_s[7][64];     // per-wave h copy (same-wave dep only)
    __shared__ float gates_s[2][G4];               // double-buffered gate pre-activations
    __shared__ __align__(16) float xv_s[2][64];    // MODE 1,2: double-buffered x_t (words 0..49 used)
    __shared__ float x_s[MODE == 0 ? TT : 1];      // MODE 0: whole input row (4 KB)

    // ---- per-thread weights: 26 + 26 named floats -> register resident ----
    HDECL(wh) HDECL(wx)
    float wxs = 0.f;
    HLOAD(wh, w_hh + pr * H, hf);
    if (MODE == 0) {
        wxs = w_ih[pr];
    } else {
        HLOAD(wx, w_ih + pr * H, hf);
    }
    const float bias = b_ih[pr] + b_hh[pr];
    float wd_r = 0.f;
    if (MODE == 2 && ln < H) wd_r = w_dense[ln];

    const float* __restrict__ xrow = xin + (size_t)b * TT * (MODE == 0 ? 1 : H);

    // ---- init LDS state + stage first inputs ----
    h_s[wv][ln] = 0.f;
    if (MODE == 0) {
        for (int i = tid; i < TT; i += BLK) x_s[i] = xrow[i];
    } else {
        if (tid < H) xv_s[0][tid] = xrow[tid];
    }
    float c_r = 0.f;     // cell state (lanes < H, replicated per wave)
    float hval = 0.f;
    __syncthreads();

    for (int t = 0; t < TT; t++) {
        const int pb = t & 1;

        // ---- spare-thread prefetch of x_{t+1}: issue loads EARLY (off critical path) ----
        float xp0 = 0.f, xp1 = 0.f;
        const int  sp   = tid - 2 * G4;                    // 0..47 for spares
        const bool pre  = (MODE != 0) && (sp >= 0) && (t + 1 < TT);
        if (pre) {
            xp0 = xrow[(size_t)(t + 1) * H + sp];          // words 0..47
            if (sp < 2) xp1 = xrow[(size_t)(t + 1) * H + 48 + sp];  // words 48,49
        }

        // ---- phase 1: half-dots (convergent for all 448 threads) ----
        float a1, tot;
        HDOT(wh, h_s[wv], hf, a1);
        if (MODE == 0) {
            tot = a1;
        } else {
            float a2;
            HDOT(wx, xv_s[pb], hf, a2);
            tot = a1 + a2;
        }
        tot += __shfl_xor(tot, 1, 64);            // pair-sum -> full 50-dot
        if (rower && hf == 0) {
            float g = tot + bias;
            if (MODE == 0) g = __fmaf_rn(wxs, x_s[t], g);
            gates_s[pb][p] = g;
        }
        // land prefetch into the OTHER buffer
        if (pre) {
            xv_s[pb ^ 1][sp] = xp0;
            if (sp < 2) xv_s[pb ^ 1][48 + sp] = xp1;
        }

        __syncthreads();   // the ONLY barrier per step

        // ---- phase 2: elementwise update, redundant in every wave ----
        if (ln < H) {
            float iv = sigm(gates_s[pb][ln]);
            float fv = sigm(gates_s[pb][H + ln]);
            float gv = tanhf_(gates_s[pb][2 * H + ln]);
            float ov = sigm(gates_s[pb][3 * H + ln]);
            c_r = __fmaf_rn(fv, c_r, iv * gv);
            hval = ov * tanhf_(c_r);
            h_s[wv][ln] = hval;
            if (MODE != 2 && wv == 0)
                hout[(size_t)b * TT * H + (size_t)t * H + ln] = hval;
        }
        // next phase-1 reads h_s[wv]: same-wave dependency -> no second barrier
    }

    // ---- dense head (MODE 2): out[b] = h_last . w_dense + b_dense ----
    if (MODE == 2 && wv == 0) {
        float v = (ln < H) ? hval * wd_r : 0.f;
#pragma unroll
        for (int off = 32; off > 0; off >>= 1) v += __shfl_down(v, off, 64);
        if (ln == 0) out[b] = v + b_dense[0];
    }
}

extern "C" void kernel_launch(void* const* d_in, const int* in_sizes, int n_in,
                              void* d_out, int out_size, void* d_ws, size_t ws_size,
                              hipStream_t stream) {
    const float* x     = (const float*)d_in[0];
    const float* wih1  = (const float*)d_in[1];
    const float* whh1  = (const float*)d_in[2];
    const float* bih1  = (const float*)d_in[3];
    const float* bhh1  = (const float*)d_in[4];
    const float* wih2  = (const float*)d_in[5];
    const float* whh2  = (const float*)d_in[6];
    const float* bih2  = (const float*)d_in[7];
    const float* bhh2  = (const float*)d_in[8];
    const float* wih3  = (const float*)d_in[9];
    const float* whh3  = (const float*)d_in[10];
    const float* bih3  = (const float*)d_in[11];
    const float* bhh3  = (const float*)d_in[12];
    const float* wd    = (const float*)d_in[13];
    const float* bd    = (const float*)d_in[14];
    float* outp = (float*)d_out;
    float* hbuf = (float*)d_ws;   // [B][T][H] fp32, used in-place by all layers

    lstm_kernel<0><<<BB, BLK, 0, stream>>>(x,    wih1, whh1, bih1, bhh1, hbuf, nullptr, nullptr, nullptr);
    lstm_kernel<1><<<BB, BLK, 0, stream>>>(hbuf, wih2, whh2, bih2, bhh2, hbuf, nullptr, nullptr, nullptr);
    lstm_kernel<2><<<BB, BLK, 0, stream>>>(hbuf, wih3, whh3, bih3, bhh3, nullptr, wd, bd, outp);
}

// Round 7
// 2615.590 us; speedup vs baseline: 1.2488x; 1.2488x over previous
//
#include <hip/hip_runtime.h>
#include <hip/hip_bf16.h>
#include <cstddef>

#define H    50
#define G4   200   // 4*H
#define TT   1024
#define BB   512
#define BLK  256   // threads per block: thread = gate row (200 active), 4 waves

__device__ __forceinline__ float sigm(float x) { return 1.0f / (1.0f + __expf(-x)); }
__device__ __forceinline__ float tanh_fast(float x) { return 1.0f - 2.0f / (__expf(2.0f * x) + 1.0f); }

__device__ __forceinline__ float4 f4mul(float4 a, float4 b) {
    return make_float4(a.x * b.x, a.y * b.y, a.z * b.z, a.w * b.w);
}
__device__ __forceinline__ float4 f4fma(float4 a, float4 b, float4 c) {
    return make_float4(__fmaf_rn(a.x, b.x, c.x), __fmaf_rn(a.y, b.y, c.y),
                       __fmaf_rn(a.z, b.z, c.z), __fmaf_rn(a.w, b.w, c.w));
}

// ---- weights as NAMED float4 registers ----
#define WDECL(P) float4 P##_q0, P##_q1, P##_q2, P##_q3, P##_q4, P##_q5, P##_q6, P##_q7, \
                        P##_q8, P##_q9, P##_q10, P##_q11; float P##_s0, P##_s1;

#define WLOAD(P, src) do { const float* _s = (src); \
    P##_q0  = make_float4(_s[0],  _s[1],  _s[2],  _s[3]);  \
    P##_q1  = make_float4(_s[4],  _s[5],  _s[6],  _s[7]);  \
    P##_q2  = make_float4(_s[8],  _s[9],  _s[10], _s[11]); \
    P##_q3  = make_float4(_s[12], _s[13], _s[14], _s[15]); \
    P##_q4  = make_float4(_s[16], _s[17], _s[18], _s[19]); \
    P##_q5  = make_float4(_s[20], _s[21], _s[22], _s[23]); \
    P##_q6  = make_float4(_s[24], _s[25], _s[26], _s[27]); \
    P##_q7  = make_float4(_s[28], _s[29], _s[30], _s[31]); \
    P##_q8  = make_float4(_s[32], _s[33], _s[34], _s[35]); \
    P##_q9  = make_float4(_s[36], _s[37], _s[38], _s[39]); \
    P##_q10 = make_float4(_s[40], _s[41], _s[42], _s[43]); \
    P##_q11 = make_float4(_s[44], _s[45], _s[46], _s[47]); \
    P##_s0 = _s[48]; P##_s1 = _s[49]; } while (0)

// vptr must be 16B-aligned LDS; 8 independent accumulation chains, depth 6.
#define WDOT(P, vptr, out) do { const float4* _v = (const float4*)(vptr); \
    float4 _a = f4mul(P##_q0, _v[0]); \
    float4 _b = f4mul(P##_q1, _v[1]); \
    _a = f4fma(P##_q2,  _v[2],  _a); _b = f4fma(P##_q3,  _v[3],  _b); \
    _a = f4fma(P##_q4,  _v[4],  _a); _b = f4fma(P##_q5,  _v[5],  _b); \
    _a = f4fma(P##_q6,  _v[6],  _a); _b = f4fma(P##_q7,  _v[7],  _b); \
    _a = f4fma(P##_q8,  _v[8],  _a); _b = f4fma(P##_q9,  _v[9],  _b); \
    _a = f4fma(P##_q10, _v[10], _a); _b = f4fma(P##_q11, _v[11], _b); \
    float _r = (_a.x + _b.x) + (_a.y + _b.y) + ((_a.z + _b.z) + (_a.w + _b.w)); \
    _r = __fmaf_rn(P##_s0, (vptr)[48], _r); \
    _r = __fmaf_rn(P##_s1, (vptr)[49], _r); \
    (out) += _r; } while (0)

// MODE 0: first layer (scalar x input, write h-seq)
// MODE 1: middle layer (vector input, write h-seq; in-place on ws is safe)
// MODE 2: last layer (vector input, no h-seq write, fused dense head)
//
// amdgpu_waves_per_eu(2,2): pin the scheduler's occupancy target to 2 waves/EU
// (VGPR budget 256) so it stops rematerializing the weight loads into the loop.
// Rounds 1/2/4/6 all came back with VGPR ~= working-set-without-weights (88/40/
// 80/48): the max-occupancy heuristic was demoting them every time.
template <int MODE>
__global__ __launch_bounds__(BLK) __attribute__((amdgpu_waves_per_eu(2, 2)))
void lstm_kernel(
    const float* __restrict__ xin,     // MODE0: x [B][T]; else h_prev [B][T][H]
    const float* __restrict__ w_ih,    // [G4][H] (MODE0: [G4][1])
    const float* __restrict__ w_hh,    // [G4][H]
    const float* __restrict__ b_ih,    // [G4]
    const float* __restrict__ b_hh,    // [G4]
    float* __restrict__ hout,          // [B][T][H]  (MODE 0,1)
    const float* __restrict__ w_dense, // [H]    (MODE 2)
    const float* __restrict__ b_dense, // [1]    (MODE 2)
    float* __restrict__ out)           // [B]    (MODE 2)
{
    const int b   = blockIdx.x;
    const int tid = threadIdx.x;
    const int wv  = tid >> 6;   // wave 0..3
    const int ln  = tid & 63;   // lane
    const int p   = tid;        // gate row (<200 active)
    const bool active = (p < G4);
    const int pr  = active ? p : (G4 - 1);   // clamp for safe loads; garbage unused

    __shared__ __align__(16) float h_s[4][64];     // per-wave h copy (same-wave dep only)
    __shared__ float gates_s[2][G4];               // double-buffered gate pre-activations
    __shared__ __align__(16) float xin_s[2][64];   // MODE 1,2: double-buffered x_t
    __shared__ float x_s[MODE == 0 ? TT : 1];      // MODE 0: whole input row (4 KB)

    // ---- weights into named float4 registers ----
    WDECL(wh) WDECL(wx)
    float wx0 = 0.f;
    WLOAD(wh, w_hh + pr * H);
    if (MODE == 0) {
        wx0 = w_ih[pr];
    } else {
        WLOAD(wx, w_ih + pr * H);
    }
    const float bias = b_ih[pr] + b_hh[pr];
    float wd_r = 0.f;
    if (MODE == 2 && ln < H) wd_r = w_dense[ln];

    const float* __restrict__ xrow = xin + (size_t)b * TT * (MODE == 0 ? 1 : H);

    // ---- init LDS state + stage first inputs ----
    h_s[wv][ln] = 0.f;
    if (MODE == 0) {
        for (int i = tid; i < TT; i += BLK) x_s[i] = xrow[i];
    } else {
        if (tid < H) xin_s[0][tid] = xrow[tid];
    }
    float c_r = 0.f;     // cell state (lanes < H, replicated per wave)
    float hval = 0.f;
    __syncthreads();

    for (int t = 0; t < TT; t++) {
        const int pbuf = t & 1;
        // ---- async prefetch of x_{t+1}: issue load EARLY, land AFTER the dots ----
        float xpre = 0.f;
        const bool pre = (MODE != 0) && (tid >= G4) && (tid < G4 + H) && (t + 1 < TT);
        if (pre) xpre = xrow[(size_t)(t + 1) * H + (tid - G4)];

        // ---- phase 1: gate pre-activation (all lanes compute; LDS reads broadcast) ----
        float acc = bias;
        WDOT(wh, h_s[wv], acc);
        if (MODE == 0) {
            acc = __fmaf_rn(wx0, x_s[t], acc);
        } else {
            WDOT(wx, xin_s[pbuf], acc);
        }
        if (active) gates_s[pbuf][p] = acc;
        if (pre) xin_s[pbuf ^ 1][tid - G4] = xpre;

        __syncthreads();   // the ONLY barrier per step

        // ---- phase 2: elementwise update, redundant in every wave ----
        if (ln < H) {
            float iv = sigm(gates_s[pbuf][ln]);
            float fv = sigm(gates_s[pbuf][H + ln]);
            float gv = tanh_fast(gates_s[pbuf][2 * H + ln]);
            float ov = sigm(gates_s[pbuf][3 * H + ln]);
            c_r = __fmaf_rn(fv, c_r, iv * gv);
            hval = ov * tanh_fast(c_r);
            h_s[wv][ln] = hval;
            if (MODE != 2 && wv == 0)
                hout[(size_t)b * TT * H + (size_t)t * H + ln] = hval;
        }
        // next phase-1 reads h_s[wv]: same-wave dependency -> no second barrier
    }

    // ---- dense head (MODE 2): out[b] = h_last . w_dense + b_dense ----
    if (MODE == 2 && wv == 0) {
        float v = (ln < H) ? hval * wd_r : 0.f;
#pragma unroll
        for (int off = 32; off > 0; off >>= 1) v += __shfl_down(v, off, 64);
        if (ln == 0) out[b] = v + b_dense[0];
    }
}

extern "C" void kernel_launch(void* const* d_in, const int* in_sizes, int n_in,
                              void* d_out, int out_size, void* d_ws, size_t ws_size,
                              hipStream_t stream) {
    const float* x     = (const float*)d_in[0];
    const float* wih1  = (const float*)d_in[1];
    const float* whh1  = (const float*)d_in[2];
    const float* bih1  = (const float*)d_in[3];
    const float* bhh1  = (const float*)d_in[4];
    const float* wih2  = (const float*)d_in[5];
    const float* whh2  = (const float*)d_in[6];
    const float* bih2  = (const float*)d_in[7];
    const float* bhh2  = (const float*)d_in[8];
    const float* wih3  = (const float*)d_in[9];
    const float* whh3  = (const float*)d_in[10];
    const float* bih3  = (const float*)d_in[11];
    const float* bhh3  = (const float*)d_in[12];
    const float* wd    = (const float*)d_in[13];
    const float* bd    = (const float*)d_in[14];
    float* outp = (float*)d_out;
    float* hbuf = (float*)d_ws;   // [B][T][H] fp32, used in-place by all layers

    lstm_kernel<0><<<BB, BLK, 0, stream>>>(x,    wih1, whh1, bih1, bhh1, hbuf, nullptr, nullptr, nullptr);
    lstm_kernel<1><<<BB, BLK, 0, stream>>>(hbuf, wih2, whh2, bih2, bhh2, hbuf, nullptr, nullptr, nullptr);
    lstm_kernel<2><<<BB, BLK, 0, stream>>>(hbuf, wih3, whh3, bih3, bhh3, nullptr, wd, bd, outp);
}